// Round 10
// baseline (1819.298 us; speedup 1.0000x reference)
//
#include <hip/hip_runtime.h>
#include <hip/hip_bf16.h>
#include <hip/hip_fp16.h>
#include <math.h>

#define N_NODES 50000
#define N_EDGES 800000
#define N_GRAPHS 128
#define ORIG_FEA 92
#define NBR_FEA 41
#define H 64
#define N_CONV 3
#define BN_EPS 1e-5f
#define KP 48        // padded K per edge row (f16): 41 real + zeros

typedef _Float16 h8 __attribute__((ext_vector_type(8)));
typedef float f32x4 __attribute__((ext_vector_type(4)));

__device__ __forceinline__ float sigmoidf_(float x) {
    return __fdividef(1.f, 1.f + __expf(-x));
}
__device__ __forceinline__ float softplusf_(float x) {
    return fmaxf(x, 0.f) + __logf(1.f + __expf(-fabsf(x)));
}

// ---------------------------------------------------------------------------
// Fold W_emb2/b_emb2/biases. Output W2frag in per-lane MFMA B-fragment order:
//   frag = (gate*4 + (j>>4))*2 + (k>>5), lane = ((k>>3)&3)*16 + (j&15),
//   elem = k&7. cfs m15-grouped: cfs[(j&15)*8 + gate*4 + (j>>4)].
// ---------------------------------------------------------------------------
__global__ __launch_bounds__(256) void fold_kernel(
    const float* __restrict__ W_emb2, const float* __restrict__ b_emb2,
    const float* __restrict__ Wf, const float* __restrict__ bf,
    const float* __restrict__ Ws, const float* __restrict__ bs,
    _Float16* __restrict__ W2frag, float* __restrict__ cfs) {
    int a = blockIdx.x >> 1, gate = blockIdx.x & 1;
    const float* W = (gate ? Ws : Wf) + a * 192 * H + 128 * H;  // [64][64]
    const float* bias = (gate ? bs : bf) + a * H;
    _Float16* out = W2frag + a * 128 * 64;
    float* cout = cfs + a * 128;
    for (int idx = threadIdx.x; idx < 64 * 64; idx += blockDim.x) {
        int j = idx >> 6, k = idx & 63;
        float acc = 0.f;
        if (k < NBR_FEA)
            for (int m = 0; m < H; ++m) acc += W_emb2[k * H + m] * W[m * H + j];
        int frag = (gate * 4 + (j >> 4)) * 2 + (k >> 5);
        int lane = (((k & 31) >> 3) << 4) + (j & 15);
        out[(frag * 64 + lane) * 8 + (k & 7)] = (_Float16)acc;
    }
    for (int j = threadIdx.x; j < H; j += blockDim.x) {
        float acc = bias[j];
        for (int m = 0; m < H; ++m) acc += b_emb2[m] * W[m * H + j];
        cout[(j & 15) * 8 + gate * 4 + (j >> 4)] = acc;
    }
}

// ---------------------------------------------------------------------------
// Wcat fragment prep for node_proj MFMA: cols = proj*64 + feat,
// proj 0=Pf(Wf_i),1=Ps(Ws_i),2=Qf(Wf_j),3=Qs(Ws_j); rows k = input feat.
// Frag-major f16, same B-frag convention as fold_kernel.
// ---------------------------------------------------------------------------
__global__ __launch_bounds__(256) void prep_wcat_kernel(
    const float* __restrict__ Wf, const float* __restrict__ Ws,
    _Float16* __restrict__ Wcat_frag) {
    int a = blockIdx.x;
    _Float16* out = Wcat_frag + a * 64 * 256;
    for (int idx = threadIdx.x; idx < 64 * 256; idx += blockDim.x) {
        int k = idx >> 8, col = idx & 255;
        int proj = col >> 6, j = col & 63;
        int gate = proj & 1, ij = proj >> 1;
        const float* W = (gate ? Ws : Wf) + a * 192 * H;
        float v = W[(ij * 64 + k) * H + j];
        int nt = col >> 4;  // proj*4 + (j>>4)
        int lane = (((k & 31) >> 3) << 4) + (j & 15);
        out[((nt * 2 + (k >> 5)) * 64 + lane) * 8 + (k & 7)] = (_Float16)v;
    }
}

// ---------------------------------------------------------------------------
// h = x @ W_emb1 + b_emb1  -> state
// ---------------------------------------------------------------------------
__global__ __launch_bounds__(256) void embed_kernel(
    const float* __restrict__ x, const float* __restrict__ W,
    const float* __restrict__ b, float* __restrict__ state) {
    __shared__ float lw[ORIG_FEA * H];
    for (int i = threadIdx.x; i < ORIG_FEA * H; i += blockDim.x) lw[i] = W[i];
    __syncthreads();
    int lane = threadIdx.x & 63;
    int wid = (blockIdx.x * blockDim.x + threadIdx.x) >> 6;
    int nw = (gridDim.x * blockDim.x) >> 6;
    for (int n = wid; n < N_NODES; n += nw) {
        int nu = __builtin_amdgcn_readfirstlane(n);
        const float* xr = x + (size_t)nu * ORIG_FEA;
        float acc = b[lane];
#pragma unroll
        for (int k = 0; k < ORIG_FEA; ++k) acc += xr[k] * lw[k * H + lane];
        state[(size_t)nu * H + lane] = acc;
    }
}

// ---------------------------------------------------------------------------
// CSR construction
// ---------------------------------------------------------------------------
__global__ __launch_bounds__(256) void hist_kernel(
    const int* __restrict__ ei, int* __restrict__ deg) {
    int e = blockIdx.x * blockDim.x + threadIdx.x;
    if (e < N_EDGES) atomicAdd(&deg[ei[N_EDGES + e]], 1);
}

__global__ __launch_bounds__(256) void scan_kernel(
    const int* __restrict__ deg, int* __restrict__ off, int* __restrict__ cur) {
    __shared__ int part[256];
    const int CHN = (N_NODES + 255) / 256;
    int t = threadIdx.x;
    int lo = t * CHN, hi = min(lo + CHN, N_NODES);
    int s = 0;
    for (int i = lo; i < hi; ++i) s += deg[i];
    part[t] = s;
    __syncthreads();
    for (int o = 1; o < 256; o <<= 1) {
        int v = (t >= o) ? part[t - o] : 0;
        __syncthreads();
        part[t] += v;
        __syncthreads();
    }
    int run = (t == 0) ? 0 : part[t - 1];
    for (int i = lo; i < hi; ++i) {
        off[i] = run;
        cur[i] = run;
        run += deg[i];
    }
    if (t == 255) off[N_NODES] = run;
}

__global__ __launch_bounds__(256) void scatter_kernel(
    const int* __restrict__ ei, int* __restrict__ cur, int* __restrict__ pos,
    int* __restrict__ src_s) {
    int e = blockIdx.x * blockDim.x + threadIdx.x;
    if (e < N_EDGES) {
        int d = ei[N_EDGES + e];
        int p = atomicAdd(&cur[d], 1);
        pos[e] = p;
        src_s[p] = ei[e];
    }
}

// ---------------------------------------------------------------------------
// Pack edge_attr -> f16 rows [KP=48] in CSR slot order.
// ---------------------------------------------------------------------------
__global__ __launch_bounds__(256) void pack_ea_kernel(
    const int* __restrict__ pos, const float* __restrict__ ea,
    _Float16* __restrict__ ea_p) {
    int lane = threadIdx.x & 63;
    int wid = (blockIdx.x * blockDim.x + threadIdx.x) >> 6;
    int nw = (gridDim.x * blockDim.x) >> 6;
    for (int e = wid; e < N_EDGES; e += nw) {
        int eu = __builtin_amdgcn_readfirstlane(e);
        int p = __builtin_amdgcn_readfirstlane(pos[eu]);
        unsigned dw = 0;
        if (lane < 21) {
            const float* er = ea + (size_t)eu * NBR_FEA;
            float v0 = er[2 * lane];
            float v1 = (2 * lane + 1 < NBR_FEA) ? er[2 * lane + 1] : 0.f;
            union { _Float16 h[2]; unsigned u; } cv;
            cv.h[0] = (_Float16)v0;
            cv.h[1] = (_Float16)v1;
            dw = cv.u;
        }
        if (lane < KP / 2)
            *(unsigned*)(ea_p + (size_t)p * KP + 2 * lane) = dw;
    }
}

// ---------------------------------------------------------------------------
// node_proj via MFMA: wave per 16-node tile (50000 = 3125*16 exact).
// A = BN(state rows) as f16; B = Wcat frags from LDS (32 KB, conflict-free);
// C = [16 nodes][256] -> NPi f32 (m15-grouped) + NPj f16 (m15-grouped f16x8).
// ---------------------------------------------------------------------------
__global__ __launch_bounds__(256, 4) void node_proj_mfma_kernel(
    const float* __restrict__ state, const float* __restrict__ stats,
    const float* __restrict__ gamma, const float* __restrict__ beta,
    const _Float16* __restrict__ Wcat_frag,
    float* __restrict__ NPi, _Float16* __restrict__ NPj, int mode) {
    __shared__ __align__(16) _Float16 lB[32 * 64 * 8];  // 32 KB
    for (int i = threadIdx.x * 8; i < 32 * 64 * 8; i += blockDim.x * 8)
        *(uint4*)(lB + i) = *(const uint4*)(Wcat_frag + i);
    __syncthreads();
    int lane = threadIdx.x & 63;
    int m15 = lane & 15, g = lane >> 4;
    // BN coefficients for this lane's k-chunks: k = ks*32 + g*8 + {0..7}
    f32x4 Ac[2][2], Bc[2][2];
#pragma unroll
    for (int ks = 0; ks < 2; ++ks)
#pragma unroll
        for (int hlf = 0; hlf < 2; ++hlf) {
            int k0 = ks * 32 + g * 8 + hlf * 4;
            if (mode) {
                const float inv_n = 1.f / (float)N_NODES;
                f32x4 sm = *(const f32x4*)(stats + k0);
                f32x4 sq = *(const f32x4*)(stats + H + k0);
                f32x4 gm = *(const f32x4*)(gamma + k0);
                f32x4 bt = *(const f32x4*)(beta + k0);
#pragma unroll
                for (int i = 0; i < 4; ++i) {
                    float mu = sm[i] * inv_n;
                    float var = sq[i] * inv_n - mu * mu;
                    float inv = rsqrtf(var + BN_EPS);
                    Ac[ks][hlf][i] = inv * gm[i];
                    Bc[ks][hlf][i] = bt[i] - mu * inv * gm[i];
                }
            } else {
                Ac[ks][hlf] = (f32x4)(1.f);
                Bc[ks][hlf] = (f32x4)(0.f);
            }
        }
    int wid = (blockIdx.x * blockDim.x + threadIdx.x) >> 6;
    int nw = (gridDim.x * blockDim.x) >> 6;
    for (int t = wid; t < 3125; t += nw) {
        int node = t * 16 + m15;
        const float* sr = state + (size_t)node * H;
        h8 afr[2];
#pragma unroll
        for (int ks = 0; ks < 2; ++ks) {
            f32x4 z0 = *(const f32x4*)(sr + ks * 32 + g * 8);
            f32x4 z1 = *(const f32x4*)(sr + ks * 32 + g * 8 + 4);
            h8 a;
#pragma unroll
            for (int i = 0; i < 4; ++i) {
                float v0 = z0[i] * Ac[ks][0][i] + Bc[ks][0][i];
                float v1 = z1[i] * Ac[ks][1][i] + Bc[ks][1][i];
                if (mode) { v0 = fmaxf(v0, 0.f); v1 = fmaxf(v1, 0.f); }
                a[i] = (_Float16)v0;
                a[4 + i] = (_Float16)v1;
            }
            afr[ks] = a;
        }
        f32x4 c[16];
#pragma unroll
        for (int nt = 0; nt < 16; ++nt) c[nt] = (f32x4)(0.f);
#pragma unroll
        for (int ks = 0; ks < 2; ++ks)
#pragma unroll
            for (int nt = 0; nt < 16; ++nt) {
                h8 b = *(const h8*)(lB + ((size_t)(nt * 2 + ks) * 64 + lane) * 8);
                c[nt] = __builtin_amdgcn_mfma_f32_16x16x32_f16(afr[ks], b, c[nt],
                                                               0, 0, 0);
            }
        // epilogue: rows 4g+r
#pragma unroll
        for (int r = 0; r < 4; ++r) {
            int nr = t * 16 + 4 * g + r;
            f32x4 lo, hi;
            h8 qj;
#pragma unroll
            for (int fq = 0; fq < 4; ++fq) {
                lo[fq] = c[fq][r];
                hi[fq] = c[4 + fq][r];
                qj[fq] = (_Float16)c[8 + fq][r];
                qj[4 + fq] = (_Float16)c[12 + fq][r];
            }
            float* pi = NPi + (size_t)nr * 128 + m15 * 8;
            *(f32x4*)pi = lo;
            *(f32x4*)(pi + 4) = hi;
            *(h8*)(NPj + (size_t)nr * 128 + m15 * 8) = qj;
        }
    }
}

// ---------------------------------------------------------------------------
// Fused edge kernel: wave per node, CSR bucket in 16-edge MFMA tiles.
// B-frags in LDS (frag-major, conflict-free b128). NPj gathers f16x8 (one
// dwordx4 per row). NPi f32 per node. BN stats fused, no atomics on state.
// ---------------------------------------------------------------------------
__global__ __launch_bounds__(256, 5) void edge_mfma_kernel(
    const int* __restrict__ off, const int* __restrict__ src_s,
    const _Float16* __restrict__ ea_p,
    const float* __restrict__ NPi, const _Float16* __restrict__ NPj,
    const _Float16* __restrict__ W2frag, const float* __restrict__ cfs,
    const float* __restrict__ stats_prev, const float* __restrict__ gamma,
    const float* __restrict__ beta, float* __restrict__ state,
    float* __restrict__ stats_out, int mode) {
    __shared__ __align__(16) _Float16 lB[128 * 64];  // 16 KB
    for (int i = threadIdx.x * 8; i < 128 * 64; i += blockDim.x * 8)
        *(uint4*)(lB + i) = *(const uint4*)(W2frag + i);
    __syncthreads();
    int lane = threadIdx.x & 63;
    int m15 = lane & 15, g = lane >> 4;
    f32x4 cflo = *(const f32x4*)(cfs + m15 * 8);
    f32x4 cfhi = *(const f32x4*)(cfs + m15 * 8 + 4);
    float A = 1.f, B = 0.f;
    if (mode) {
        const float inv_n = 1.f / (float)N_NODES;
        float mu = stats_prev[lane] * inv_n;
        float var = stats_prev[H + lane] * inv_n - mu * mu;
        float inv = rsqrtf(var + BN_EPS);
        A = inv * gamma[lane];
        B = beta[lane] - mu * A;
    }
    float s = 0.f, s2 = 0.f;
    int wid = (blockIdx.x * blockDim.x + threadIdx.x) >> 6;
    int nw = (gridDim.x * blockDim.x) >> 6;
    for (int n = wid; n < N_NODES; n += nw) {
        int nu = __builtin_amdgcn_readfirstlane(n);
        float z = state[(size_t)nu * H + lane];
        float acc = mode ? fmaxf(z * A + B, 0.f) : z;  // residual h
        f32x4 nplo = *(const f32x4*)(NPi + (size_t)nu * 128 + m15 * 8);
        f32x4 nphi = *(const f32x4*)(NPi + (size_t)nu * 128 + m15 * 8 + 4);
        f32x4 bfv = cflo + nplo;
        f32x4 bsv = cfhi + nphi;
        int e0 = __builtin_amdgcn_readfirstlane(off[nu]);
        int e1 = __builtin_amdgcn_readfirstlane(off[nu + 1]);
        for (int e = e0; e < e1; e += 16) {
            int cnt = e1 - e;
            // A fragments
            int arow = e + (m15 < cnt ? m15 : 0);
            const _Float16* rowp = ea_p + (size_t)arow * KP;
            h8 afr0, afr1;
            {
                union { uint4 u; h8 h; } cv0, cv1;
                cv0.u = *(const uint4*)(rowp + g * 8);
                afr0 = cv0.h;
                const _Float16* p1 = rowp + ((g < 2) ? (32 + g * 8) : 0);
                uint4 r1 = *(const uint4*)p1;
                if (g >= 2) { r1.x = 0u; r1.y = 0u; r1.z = 0u; r1.w = 0u; }
                cv1.u = r1;
                afr1 = cv1.h;
            }
            // NPj gathers (4 rows x 1 dwordx4 f16, independent chains)
            h8 ql[4];
            float mul[4];
#pragma unroll
            for (int r = 0; r < 4; ++r) {
                int rr = 4 * g + r;
                int ee = e + ((rr < cnt) ? rr : (cnt - 1));
                int sv = src_s[ee];
                ql[r] = *(const h8*)(NPj + (size_t)sv * 128 + m15 * 8);
                mul[r] = (rr < cnt) ? 1.f : 0.f;
            }
            f32x4 c[8];
#pragma unroll
            for (int nt = 0; nt < 8; ++nt) c[nt] = (f32x4)(0.f);
#pragma unroll
            for (int nt = 0; nt < 8; ++nt) {
                h8 b = *(const h8*)(lB + ((size_t)(nt * 2) * 64 + lane) * 8);
                c[nt] = __builtin_amdgcn_mfma_f32_16x16x32_f16(afr0, b, c[nt],
                                                               0, 0, 0);
            }
#pragma unroll
            for (int nt = 0; nt < 8; ++nt) {
                h8 b = *(const h8*)(lB + ((size_t)(nt * 2 + 1) * 64 + lane) * 8);
                c[nt] = __builtin_amdgcn_mfma_f32_16x16x32_f16(afr1, b, c[nt],
                                                               0, 0, 0);
            }
            float ts0 = 0.f, ts1 = 0.f, ts2 = 0.f, ts3 = 0.f;
#pragma unroll
            for (int r = 0; r < 4; ++r) {
                {
                    float af = c[0][r] + bfv[0] + (float)ql[r][0];
                    float as = c[4][r] + bsv[0] + (float)ql[r][4];
                    ts0 += mul[r] * sigmoidf_(af) * softplusf_(as);
                }
                {
                    float af = c[1][r] + bfv[1] + (float)ql[r][1];
                    float as = c[5][r] + bsv[1] + (float)ql[r][5];
                    ts1 += mul[r] * sigmoidf_(af) * softplusf_(as);
                }
                {
                    float af = c[2][r] + bfv[2] + (float)ql[r][2];
                    float as = c[6][r] + bsv[2] + (float)ql[r][6];
                    ts2 += mul[r] * sigmoidf_(af) * softplusf_(as);
                }
                {
                    float af = c[3][r] + bfv[3] + (float)ql[r][3];
                    float as = c[7][r] + bsv[3] + (float)ql[r][7];
                    ts3 += mul[r] * sigmoidf_(af) * softplusf_(as);
                }
            }
            ts0 += __shfl_xor(ts0, 16, 64); ts0 += __shfl_xor(ts0, 32, 64);
            ts1 += __shfl_xor(ts1, 16, 64); ts1 += __shfl_xor(ts1, 32, 64);
            ts2 += __shfl_xor(ts2, 16, 64); ts2 += __shfl_xor(ts2, 32, 64);
            ts3 += __shfl_xor(ts3, 16, 64); ts3 += __shfl_xor(ts3, 32, 64);
            float v = (g & 2) ? ((g & 1) ? ts3 : ts2) : ((g & 1) ? ts1 : ts0);
            acc += v;
        }
        state[(size_t)nu * H + lane] = acc;
        s += acc;
        s2 += acc * acc;
    }
    atomicAdd(&stats_out[lane], s);
    atomicAdd(&stats_out[H + lane], s2);
}

// ---------------------------------------------------------------------------
// Pool with fused final BN (sorted batch: local accumulate, flush on change)
// ---------------------------------------------------------------------------
__global__ __launch_bounds__(256) void pool_bn_kernel(
    const float* __restrict__ state, const float* __restrict__ stats,
    const float* __restrict__ gamma, const float* __restrict__ beta,
    const int* __restrict__ batch, float* __restrict__ gsum,
    float* __restrict__ gcnt) {
    int lane = threadIdx.x & 63;
    const float inv_n = 1.f / (float)N_NODES;
    float mu = stats[lane] * inv_n;
    float var = stats[H + lane] * inv_n - mu * mu;
    float inv = rsqrtf(var + BN_EPS);
    float A = inv * gamma[lane];
    float B = beta[lane] - mu * A;
    int wid = (blockIdx.x * blockDim.x + threadIdx.x) >> 6;
    int nw = (gridDim.x * blockDim.x) >> 6;
    int per = (N_NODES + nw - 1) / nw;
    int lo = wid * per, hi = min(lo + per, N_NODES);
    if (lo >= hi) return;
    int gcur = __builtin_amdgcn_readfirstlane(batch[lo]);
    float accv = 0.f, cntv = 0.f;
    for (int n = lo; n < hi; ++n) {
        int gn = __builtin_amdgcn_readfirstlane(batch[n]);
        if (gn != gcur) {
            atomicAdd(&gsum[(size_t)gcur * H + lane], accv);
            if (lane == 0) atomicAdd(&gcnt[gcur], cntv);
            gcur = gn;
            accv = 0.f;
            cntv = 0.f;
        }
        accv += state[(size_t)n * H + lane] * A + B;
        cntv += 1.f;
    }
    atomicAdd(&gsum[(size_t)gcur * H + lane], accv);
    if (lane == 0) atomicAdd(&gcnt[gcur], cntv);
}

__global__ __launch_bounds__(64) void mlp_kernel(
    const float* __restrict__ gsum, const float* __restrict__ gcnt,
    const float* __restrict__ W1, const float* __restrict__ b1,
    const float* __restrict__ W2, const float* __restrict__ b2,
    const float* __restrict__ Wo, const float* __restrict__ bo,
    float* __restrict__ out) {
    int g = blockIdx.x;
    int lane = threadIdx.x;
    __shared__ float y[H];
    float cnt = fmaxf(gcnt[g], 1.f);
    y[lane] = gsum[(size_t)g * H + lane] / cnt;
    __syncthreads();
    float acc = b1[lane];
#pragma unroll
    for (int k = 0; k < H; ++k) acc += y[k] * W1[k * H + lane];
    float y1 = softplusf_(acc);
    __syncthreads();
    y[lane] = y1;
    __syncthreads();
    acc = b2[lane];
#pragma unroll
    for (int k = 0; k < H; ++k) acc += y[k] * W2[k * H + lane];
    float y2 = softplusf_(acc);
    float t = y2 * Wo[lane];
#pragma unroll
    for (int o = 32; o > 0; o >>= 1) t += __shfl_down(t, o, 64);
    if (lane == 0) out[g] = t + bo[0];
}

extern "C" void kernel_launch(void* const* d_in, const int* in_sizes, int n_in,
                              void* d_out, int out_size, void* d_ws, size_t ws_size,
                              hipStream_t stream) {
    const float* x = (const float*)d_in[0];
    const float* ea = (const float*)d_in[1];
    const int* ei = (const int*)d_in[2];
    const int* batch = (const int*)d_in[3];
    const float* W_emb1 = (const float*)d_in[4];
    const float* b_emb1 = (const float*)d_in[5];
    const float* W_emb2 = (const float*)d_in[6];
    const float* b_emb2 = (const float*)d_in[7];
    const float* Wf = (const float*)d_in[8];
    const float* bf = (const float*)d_in[9];
    const float* Ws = (const float*)d_in[10];
    const float* bs = (const float*)d_in[11];
    const float* gamma = (const float*)d_in[12];
    const float* beta = (const float*)d_in[13];
    const float* W1 = (const float*)d_in[14];
    const float* b1 = (const float*)d_in[15];
    const float* W2 = (const float*)d_in[16];
    const float* b2 = (const float*)d_in[17];
    const float* Wo = (const float*)d_in[18];
    const float* bo = (const float*)d_in[19];
    float* out = (float*)d_out;

    float* w = (float*)d_ws;
    // ---- zeroed region ----
    float* stats = w;                          // 384
    float* gsum = stats + 3 * 2 * H;           // 8192
    float* gcnt = gsum + N_GRAPHS * H;         // 128
    int* deg = (int*)(gcnt + N_GRAPHS);        // 50000
    const size_t zero_elems = 3 * 2 * H + N_GRAPHS * H + N_GRAPHS + N_NODES;
    // ---- scratch ----
    _Float16* ea_p = (_Float16*)(w + zero_elems);          // (800008)*48 f16
    int* off = (int*)(ea_p + (size_t)(N_EDGES + 8) * KP);  // 50004
    int* cur = off + 50004;                                // 50000
    int* pos = cur + N_NODES;                              // 800000
    int* src_s = pos + N_EDGES;                            // 800000
    _Float16* W2frag = (_Float16*)(src_s + N_EDGES);       // 3*8192 f16
    _Float16* Wcat_frag = W2frag + 3 * 128 * 64;           // 3*16384 f16
    float* cfs = (float*)(Wcat_frag + 3 * 64 * 256);       // 3*128
    float* state = cfs + 3 * 128;                          // 3.2M f32
    float* NPi = state + (size_t)N_NODES * H;              // 6.4M f32
    _Float16* NPj = (_Float16*)(NPi + (size_t)N_NODES * 128);  // 6.4M f16
    // total ~135 MB

    hipMemsetAsync(w, 0, zero_elems * sizeof(float), stream);

    fold_kernel<<<6, 256, 0, stream>>>(W_emb2, b_emb2, Wf, bf, Ws, bs, W2frag, cfs);
    prep_wcat_kernel<<<3, 256, 0, stream>>>(Wf, Ws, Wcat_frag);
    embed_kernel<<<512, 256, 0, stream>>>(x, W_emb1, b_emb1, state);
    hist_kernel<<<(N_EDGES + 255) / 256, 256, 0, stream>>>(ei, deg);
    scan_kernel<<<1, 256, 0, stream>>>(deg, off, cur);
    scatter_kernel<<<(N_EDGES + 255) / 256, 256, 0, stream>>>(ei, cur, pos, src_s);
    pack_ea_kernel<<<2048, 256, 0, stream>>>(pos, ea, ea_p);

    for (int a = 0; a < N_CONV; ++a) {
        const float* sp = a > 0 ? stats + (a - 1) * 2 * H : stats;
        const float* gp = a > 0 ? gamma + (a - 1) * H : gamma;
        const float* bp = a > 0 ? beta + (a - 1) * H : beta;
        int mode = a > 0 ? 1 : 0;
        node_proj_mfma_kernel<<<512, 256, 0, stream>>>(
            state, sp, gp, bp, Wcat_frag + a * 64 * 256, NPi, NPj, mode);
        edge_mfma_kernel<<<1280, 256, 0, stream>>>(
            off, src_s, ea_p, NPi, NPj, W2frag + a * 128 * 64, cfs + a * 128,
            sp, gp, bp, state, stats + a * 2 * H, mode);
    }

    pool_bn_kernel<<<784, 256, 0, stream>>>(state, stats + 2 * 2 * H,
                                            gamma + 2 * H, beta + 2 * H,
                                            batch, gsum, gcnt);
    mlp_kernel<<<128, 64, 0, stream>>>(gsum, gcnt, W1, b1, W2, b2, Wo, bo, out);
}